// Round 5
// baseline (794.718 us; speedup 1.0000x reference)
//
#include <hip/hip_runtime.h>

#define T_STEPS 500
#define BATCH   128
#define NINPUT  6
#define NH      500
#define THRV    1.0f
#define BETAV   0.5f
#define W2T_STRIDE 512
#define NGC     8      // j-chunks of 64 outputs
#define NB      4      // batch elements per block
#define NW      8      // waves per block (64 layer-1 rows each)
#define ZROW    500    // zero row index in W2L (padding target)

typedef unsigned long long ull;

// ---------------------------------------------------------------------------
// Transpose W2 [500][500] -> W2T [500][512] (padded stride, pad zeroed).
// ---------------------------------------------------------------------------
__global__ void transpose_w2(const float* __restrict__ W2, float* __restrict__ W2T) {
  int idx = blockIdx.x * 256 + threadIdx.x;
  if (idx < NH * W2T_STRIDE) {
    int i = idx >> 9;          // input neuron (row of W2T)
    int j = idx & 511;         // output neuron (contiguous write)
    W2T[idx] = (j < NH) ? W2[j * NH + i] : 0.f;
  }
}

// ---------------------------------------------------------------------------
// Phase A: layers 1+2 recurrence. grid = (BATCH/NB=32, NGC=8), 512 threads.
// Block: 4 batch elements, 64-output j-chunk. W2 chunk lives in LDS (fp32,
// [501][64], row 500 = zeros for padding). Wave w owns layer-1 rows
// [64w, 64w+64) for all 4 batches; sparse accumulation reads ds_read_b32
// (flat 8 slots per batch, zero-row padded, all loads issued before any
// accumulate -> one latency). Waves 0-3 each combine one batch's partials,
// update m2, ballot; s2 masks buffered in registers, flushed every 64 steps.
// ---------------------------------------------------------------------------
__global__ __launch_bounds__(512, 2) void phase_a(
    const float* __restrict__ x,     // [T][B][6]
    const float* __restrict__ W1,    // [500][6]
    const float* __restrict__ b1,    // [500]
    const float* __restrict__ b2,    // [500]
    const float* __restrict__ W2T,   // [500][512]
    ull* __restrict__ s2bits)        // [T][B][NGC]
{
  const int b0   = blockIdx.x * NB;
  const int ng   = blockIdx.y;
  const int wid  = threadIdx.x >> 6;
  const int lane = threadIdx.x & 63;

  __shared__ float W2L[(NH + 1) * 64];        // 128256 B
  __shared__ float part[2][NW][NB][64];       // 16384 B

  // ---- stage W2 chunk into LDS (coalesced from W2T) ----
  const int jbase = ng * 64;
  for (int idx = threadIdx.x; idx < (NH + 1) * 64; idx += 512) {
    int i = idx >> 6, jl = idx & 63;
    W2L[idx] = (i < NH) ? W2T[i * W2T_STRIDE + jbase + jl] : 0.f;
  }

  // ---- layer-1 static data: row n for all NB batches ----
  const int n  = (wid << 6) + lane;
  const bool nv = (n < NH);
  float w1r[6], b1v;
  #pragma unroll
  for (int k = 0; k < 6; ++k) w1r[k] = nv ? W1[n * NINPUT + k] : 0.f;
  b1v = nv ? b1[n] : 0.f;
  float m1[NB];
  #pragma unroll
  for (int bi = 0; bi < NB; ++bi) m1[bi] = 0.f;

  // ---- combine role: wave w (<NB) owns batch b0+w ----
  const int j  = jbase + lane;
  const bool jv = (j < NH);
  const float b2v = (wid < NB && jv) ? b2[j] : 0.f;
  float m2 = 0.f;
  ull keep = 0;

  float xa[NB][6], xb[NB][6];

  #define LOADX(tt, xr) do {                                              \
    _Pragma("unroll")                                                     \
    for (int bi_ = 0; bi_ < NB; ++bi_) {                                  \
      const float* xp_ = x + (size_t)((tt) * BATCH + b0 + bi_) * NINPUT;  \
      float2 a_ = *(const float2*)xp_;                                    \
      float2 c_ = *(const float2*)(xp_ + 2);                              \
      float2 d_ = *(const float2*)(xp_ + 4);                              \
      xr[bi_][0]=a_.x; xr[bi_][1]=a_.y; xr[bi_][2]=c_.x;                  \
      xr[bi_][3]=c_.y; xr[bi_][4]=d_.x; xr[bi_][5]=d_.y;                  \
    }                                                                     \
  } while (0)

  #define STEP1(xr, masks) do {                                           \
    _Pragma("unroll")                                                     \
    for (int bi_ = 0; bi_ < NB; ++bi_) {                                  \
      float cur_ = b1v + w1r[0]*xr[bi_][0] + w1r[1]*xr[bi_][1]            \
                 + w1r[2]*xr[bi_][2] + w1r[3]*xr[bi_][3]                  \
                 + w1r[4]*xr[bi_][4] + w1r[5]*xr[bi_][5];                 \
      float rst_ = (m1[bi_] > THRV) ? THRV : 0.f;                         \
      m1[bi_] = BETAV * m1[bi_] + cur_ - rst_;                            \
      masks[bi_] = __ballot((m1[bi_] > THRV) && nv);                      \
    }                                                                     \
  } while (0)

  // Sparse accumulate from LDS. All 4 batches: extract up to 8 ascending
  // row indices (pad with ZROW), issue all 32 ds_read_b32, then accumulate
  // left-assoc ascending (bit-exact vs sequential sparse sum; +0.0 pads are
  // exact no-ops). Rare overflow (>8 active) handled by a scalar peel.
  #define SPARSE(masks, a) do {                                           \
    float v_[NB][8];                                                      \
    ull rem_[NB];                                                         \
    _Pragma("unroll")                                                     \
    for (int bi_ = 0; bi_ < NB; ++bi_) {                                  \
      ull m_ = masks[bi_];                                                \
      _Pragma("unroll")                                                   \
      for (int s_ = 0; s_ < 8; ++s_) {                                    \
        int row_ = (m_ != 0) ? ((wid << 6) + __builtin_ctzll(m_)) : ZROW; \
        m_ &= m_ - 1;                                                     \
        v_[bi_][s_] = W2L[row_ * 64 + lane];                              \
      }                                                                   \
      rem_[bi_] = m_;                                                     \
    }                                                                     \
    _Pragma("unroll")                                                     \
    for (int bi_ = 0; bi_ < NB; ++bi_) {                                  \
      float acc_ = 0.f;                                                   \
      _Pragma("unroll")                                                   \
      for (int s_ = 0; s_ < 8; ++s_) acc_ += v_[bi_][s_];                 \
      a[bi_] = acc_;                                                      \
    }                                                                     \
    _Pragma("unroll")                                                     \
    for (int bi_ = 0; bi_ < NB; ++bi_) {                                  \
      if (rem_[bi_]) {                                                    \
        ull m_ = rem_[bi_];                                               \
        while (m_) {                                                      \
          int row_ = (wid << 6) + __builtin_ctzll(m_); m_ &= m_ - 1;      \
          a[bi_] += W2L[row_ * 64 + lane];                                \
        }                                                                 \
      }                                                                   \
    }                                                                     \
  } while (0)

  // Combine step t (waves 0..NB-1 only), LIF, ballot, keep/flush.
  #define COMBINE(t) do {                                                 \
    const int pb_ = (t) & 1;                                              \
    if (wid < NB) {                                                       \
      float p0 = part[pb_][0][wid][lane], p1 = part[pb_][1][wid][lane],   \
            p2 = part[pb_][2][wid][lane], p3 = part[pb_][3][wid][lane],   \
            p4 = part[pb_][4][wid][lane], p5 = part[pb_][5][wid][lane],   \
            p6 = part[pb_][6][wid][lane], p7 = part[pb_][7][wid][lane];   \
      float cur_ = (((p0 + p1) + (p2 + p3)) +                             \
                    ((p4 + p5) + (p6 + p7))) + b2v;                       \
      float rst_ = (m2 > THRV) ? THRV : 0.f;                              \
      m2 = BETAV * m2 + cur_ - rst_;                                      \
      ull bm_ = __ballot((m2 > THRV) && jv);                              \
      keep = (lane == ((t) & 63)) ? bm_ : keep;                           \
      if (((t) & 63) == 63) {                                             \
        s2bits[((size_t)(((t) - 63) + lane) * BATCH + b0 + wid) * NGC + ng] = keep; \
      }                                                                   \
    }                                                                     \
  } while (0)

  // ---- prologue ----
  LOADX(0, xa);
  ull mask[NB];
  STEP1(xa, mask);               // masks for t=0
  LOADX(1, xa);                  // xa now holds x[1]
  __syncthreads();               // W2L staged
  float a[NB];
  SPARSE(mask, a);
  #pragma unroll
  for (int bi = 0; bi < NB; ++bi) part[0][wid][bi][lane] = a[bi];
  __syncthreads();

  for (int t = 0; t < T_STEPS - 1; ++t) {
    int tp = t + 2; if (tp > T_STEPS - 1) tp = T_STEPS - 1;
    LOADX(tp, xb);
    STEP1(xa, mask);             // masks for t+1
    SPARSE(mask, a);             // LDS loads for t+1
    COMBINE(t);                  // overlaps with sparse-load latency
    const int pb = t & 1;
    #pragma unroll
    for (int bi = 0; bi < NB; ++bi) part[pb ^ 1][wid][bi][lane] = a[bi];
    __syncthreads();
    #pragma unroll
    for (int bi = 0; bi < NB; ++bi)
      #pragma unroll
      for (int k = 0; k < 6; ++k) xa[bi][k] = xb[bi][k];
  }

  // ---- epilogue: t = T_STEPS-1, then final partial flush (t 448..499) ----
  COMBINE(T_STEPS - 1);
  if (wid < NB && lane < (T_STEPS - 448)) {
    s2bits[((size_t)(448 + lane) * BATCH + b0 + wid) * NGC + ng] = keep;
  }
  #undef LOADX
  #undef STEP1
  #undef SPARSE
  #undef COMBINE
}

// ---------------------------------------------------------------------------
// B1: cur3[t][b][2] = Wout . s2[t][b] -- fully parallel over (t,b).
// s2bits layout [T][B][NGC], word g bit l <-> j = g*64+l.
// ---------------------------------------------------------------------------
__global__ __launch_bounds__(256) void cur3_kernel(
    const ull* __restrict__ s2bits,
    const float* __restrict__ Wout,  // [2][500]
    float* __restrict__ cur3)        // [T*B][2]
{
  const int wid  = threadIdx.x >> 6;
  const int lane = threadIdx.x & 63;
  const int pair = blockIdx.x * 4 + wid;   // t*BATCH + b
  if (pair >= T_STEPS * BATCH) return;

  float wa[NGC], wb[NGC];
  #pragma unroll
  for (int g = 0; g < NGC; ++g) {
    int j = g * 64 + lane;
    wa[g] = (j < NH) ? Wout[j] : 0.f;
    wb[g] = (j < NH) ? Wout[NH + j] : 0.f;
  }

  const ull* p = s2bits + (size_t)pair * NGC;
  float c0 = 0.f, c1 = 0.f;
  #pragma unroll
  for (int g = 0; g < NGC; ++g) {
    ull mg = p[g];
    if ((mg >> lane) & 1ull) { c0 += wa[g]; c1 += wb[g]; }
  }
  #pragma unroll
  for (int off = 32; off; off >>= 1) {
    c0 += __shfl_xor(c0, off);
    c1 += __shfl_xor(c1, off);
  }
  if (lane == 0) *(float2*)(cur3 + (size_t)pair * 2) = make_float2(c0, c1);
}

// ---------------------------------------------------------------------------
// B2: serial m3 scan, one thread per batch element, 8-deep static prefetch.
// ---------------------------------------------------------------------------
__global__ __launch_bounds__(128) void scan3_kernel(
    const float* __restrict__ cur3,  // [T*B][2]
    const float* __restrict__ bout,  // [2]
    float* __restrict__ out)         // spk [T][B][2] then mem [T][B][2]
{
  const int b = threadIdx.x;
  const float bo0 = bout[0], bo1 = bout[1];
  float m0 = 0.f, m1v = 0.f;

  float2 cbuf[8], nbuf[8];
  #pragma unroll
  for (int k = 0; k < 8; ++k)
    cbuf[k] = *(const float2*)(cur3 + (size_t)(k * BATCH + b) * 2);

  for (int tc = 0; tc < T_STEPS; tc += 8) {
    #pragma unroll
    for (int k = 0; k < 8; ++k) {
      int tn = tc + 8 + k; if (tn > T_STEPS - 1) tn = T_STEPS - 1;
      nbuf[k] = *(const float2*)(cur3 + (size_t)(tn * BATCH + b) * 2);
    }
    #pragma unroll
    for (int k = 0; k < 8; ++k) {
      int t = tc + k;
      if (t < T_STEPS) {
        float c0 = cbuf[k].x + bo0, c1 = cbuf[k].y + bo1;
        float r0 = (m0  > THRV) ? THRV : 0.f;
        float r1 = (m1v > THRV) ? THRV : 0.f;
        m0  = BETAV * m0  + c0 - r0;
        m1v = BETAV * m1v + c1 - r1;
        size_t o = (size_t)(t * BATCH + b) * 2;
        out[o]     = (m0  > THRV) ? 1.f : 0.f;
        out[o + 1] = (m1v > THRV) ? 1.f : 0.f;
        out[(size_t)T_STEPS * BATCH * 2 + o]     = m0;
        out[(size_t)T_STEPS * BATCH * 2 + o + 1] = m1v;
      }
    }
    #pragma unroll
    for (int k = 0; k < 8; ++k) cbuf[k] = nbuf[k];
  }
}

extern "C" void kernel_launch(void* const* d_in, const int* in_sizes, int n_in,
                              void* d_out, int out_size, void* d_ws, size_t ws_size,
                              hipStream_t stream) {
  const float* x    = (const float*)d_in[0];
  const float* W1   = (const float*)d_in[1];
  const float* b1   = (const float*)d_in[2];
  const float* W2   = (const float*)d_in[3];
  const float* b2   = (const float*)d_in[4];
  const float* Wout = (const float*)d_in[5];
  const float* bout = (const float*)d_in[6];
  float* out = (float*)d_out;

  // ws layout: s2bits [0, 4.096 MB) | W2T [4.096, 5.12 MB)
  // cur3 (512 KB) reuses the W2T region (W2T dead after phase_a).
  ull*   s2bits = (ull*)d_ws;
  float* W2T    = (float*)((char*)d_ws + (size_t)T_STEPS * BATCH * NGC * sizeof(ull));
  float* cur3   = W2T;

  transpose_w2<<<(NH * W2T_STRIDE + 255) / 256, 256, 0, stream>>>(W2, W2T);
  phase_a<<<dim3(BATCH / NB, NGC), 512, 0, stream>>>(x, W1, b1, b2, W2T, s2bits);
  cur3_kernel<<<(T_STEPS * BATCH + 3) / 4, 256, 0, stream>>>(s2bits, Wout, cur3);
  scan3_kernel<<<1, 128, 0, stream>>>(cur3, bout, out);
}